// Round 2
// baseline (209.701 us; speedup 1.0000x reference)
//
#include <hip/hip_runtime.h>
#include <hip/hip_bf16.h>

// Proto contrastive loss, MI355X.
// B=2, E=256, HW=1024, C=80, Q=1024.
// SE[p][c] = sum_q exp(dot(featn_p, queue_qc)/TEMP); lse's collapse algebraically.
// Queue rows 0,1 (unit-norm prototypes, |logit|<=14.3) are zeroed in the bf16 GEMM
// and added back in fp32 (exp2(0)=1 each -> subtract 2). Remaining rows |logit|<=1.43.

#define B_ 2
#define E_ 256
#define HW_ 1024
#define C_ 80
#define Q_ 1024
#define NPIX (B_*HW_)

typedef __attribute__((ext_vector_type(4))) float f32x4;
typedef __attribute__((ext_vector_type(8))) short bf16x8;
typedef unsigned int u32;
typedef __attribute__((ext_vector_type(4))) u32 u32x4;

#define L2E 1.4426950408889634f
#define SCALE_A (L2E / 0.07f)
#define INV_TEMP (1.0f / 0.07f)

__device__ __forceinline__ float wred_sum(float v) {
#pragma unroll
  for (int m = 1; m < 64; m <<= 1) v += __shfl_xor(v, m, 64);
  return v;
}
__device__ __forceinline__ float wred_max(float v) {
#pragma unroll
  for (int m = 1; m < 64; m <<= 1) v = fmaxf(v, __shfl_xor(v, m, 64));
  return v;
}

// ---------------- zero the atomic accumulators ----------------
__global__ void k_zero(float* cs, float* cc) {
  int t = threadIdx.x;
  if (t < C_) { cs[t] = 0.f; cc[t] = 0.f; }
}

// ---------------- softmax(score/0.001) over C, per pixel ----------------
__global__ void k_sm(const float* __restrict__ score, float* __restrict__ SM) {
  int w = threadIdx.x >> 6, l = threadIdx.x & 63;
  int p = blockIdx.x * 4 + w;
  int b = p >> 10, h = p & 1023;
  float x0 = score[((size_t)(b*C_ + l))*HW_ + h] * 1000.0f;
  float x1 = (l < C_ - 64) ? score[((size_t)(b*C_ + 64 + l))*HW_ + h] * 1000.0f : -__builtin_inff();
  float m = wred_max(fmaxf(x0, x1));
  float e0 = __builtin_amdgcn_exp2f((x0 - m) * L2E);
  float e1 = (l < C_ - 64) ? __builtin_amdgcn_exp2f((x1 - m) * L2E) : 0.0f;
  float s = wred_sum(e0 + e1);
  float inv = 1.0f / s;
  SM[(size_t)p*C_ + l] = e0 * inv;
  if (l < C_ - 64) SM[(size_t)p*C_ + 64 + l] = e1 * inv;
}

// ---------------- per-pixel L2 norm; write featn fp32 + scaled bf16 A ----------------
__global__ void k_featn(const float* __restrict__ feat, float* __restrict__ FEATN,
                        float* __restrict__ NORM, __hip_bfloat16* __restrict__ ABF) {
  int w = threadIdx.x >> 6, l = threadIdx.x & 63;
  int p = blockIdx.x * 4 + w;
  int b = p >> 10, h = p & 1023;
  float f[4]; float ss = 0.f;
#pragma unroll
  for (int i = 0; i < 4; i++) {
    int e = l + 64*i;
    f[i] = feat[((size_t)(b*E_ + e))*HW_ + h];
    ss += f[i]*f[i];
  }
  ss = wred_sum(ss);
  float nrm = sqrtf(ss);
  float inv = 1.0f / fmaxf(nrm, 1e-5f);
#pragma unroll
  for (int i = 0; i < 4; i++) {
    int e = l + 64*i;
    float v = f[i]*inv;
    FEATN[(size_t)p*E_ + e] = v;
    ABF[(size_t)p*E_ + e] = __float2bfloat16(v * SCALE_A);
  }
  if (l == 0) NORM[p] = nrm;
}

// ---------------- prototypes: partial einsum feat * (sm|cm) ----------------
__global__ void k_protos(const float* __restrict__ SM, const float* __restrict__ cmap,
                         const float* __restrict__ FEATN, const float* __restrict__ NORM,
                         float* __restrict__ PART) {
  int hch = blockIdx.x, b = blockIdx.y;
  int map = blockIdx.z >> 1, ch = blockIdx.z & 1;
  int e = threadIdx.x;
  __shared__ float wl[64][40];
  for (int idx = threadIdx.x; idx < 64*40; idx += 256) {
    int ii = idx / 40, cl = idx % 40;
    int c = ch*40 + cl;
    int p = b*HW_ + hch*64 + ii;
    int h = p & 1023;
    float wv = (map == 0) ? SM[(size_t)p*C_ + c] : cmap[((size_t)(b*C_ + c))*HW_ + h];
    wl[ii][cl] = wv * NORM[p];
  }
  __syncthreads();
  float acc[40];
#pragma unroll
  for (int j = 0; j < 40; j++) acc[j] = 0.f;
  for (int ii = 0; ii < 64; ii++) {
    int p = b*HW_ + hch*64 + ii;
    float f = FEATN[(size_t)p*E_ + e];
#pragma unroll
    for (int j = 0; j < 40; j++) acc[j] += f * wl[ii][j];
  }
  float* out = PART + ((size_t)(hch*4 + map*2 + b)*E_ + e)*C_ + ch*40;
#pragma unroll
  for (int j = 0; j < 40; j++) out[j] = acc[j];
}

// reduce 32 chunks -> PROT[map][b][e][c]
__global__ void k_protred(const float* __restrict__ PART, float* __restrict__ PROT) {
  int g = blockIdx.x*256 + threadIdx.x;   // 81920
  float s = 0.f;
#pragma unroll 8
  for (int chk = 0; chk < 32; chk++) s += PART[(size_t)chk*81920 + g];
  PROT[g] = s;
}

// L2-normalize PROT over e for each (map,b,c)
__global__ void k_norm(float* PROT) {
  int w = threadIdx.x >> 6, l = threadIdx.x & 63;
  int gid = blockIdx.x*4 + w;          // 320
  int mb = gid / C_, c = gid % C_;
  float v[4]; float ss = 0.f;
#pragma unroll
  for (int i = 0; i < 4; i++) {
    v[i] = PROT[((size_t)(mb*E_ + l + 64*i))*C_ + c];
    ss += v[i]*v[i];
  }
  ss = wred_sum(ss);
  float inv = 1.0f / fmaxf(sqrtf(ss), 1e-5f);
#pragma unroll
  for (int i = 0; i < 4; i++)
    PROT[((size_t)(mb*E_ + l + 64*i))*C_ + c] = v[i]*inv;
}

// ---------------- queue -> bf16 [c][q][e]; rows 0,1 ZEROED (handled in fp32) ----------------
__global__ void k_transpose(const float* __restrict__ queue,
                            __hip_bfloat16* __restrict__ QB) {
  int q = blockIdx.x, t = threadIdx.x;
  if (q < B_) {
#pragma unroll 4
    for (int c = 0; c < C_; c++)
      QB[((size_t)c*Q_ + q)*E_ + t] = __float2bfloat16(0.0f);
    return;
  }
  const float* src = queue + (size_t)q*E_*C_;
#pragma unroll 4
  for (int c = 0; c < C_; c += 4) {
    float4 v = *(const float4*)(src + (size_t)t*C_ + c);
    QB[((size_t)(c+0)*Q_ + q)*E_ + t] = __float2bfloat16(v.x);
    QB[((size_t)(c+1)*Q_ + q)*E_ + t] = __float2bfloat16(v.y);
    QB[((size_t)(c+2)*Q_ + q)*E_ + t] = __float2bfloat16(v.z);
    QB[((size_t)(c+3)*Q_ + q)*E_ + t] = __float2bfloat16(v.w);
  }
}

// ---------------- main: SEg[p][c] = sum_q exp2(acc)  (rows 0,1 contribute 1 each) ----------------
__launch_bounds__(256, 2)
__global__ void k_gemm(const short* __restrict__ A, const short* __restrict__ QB,
                       float* __restrict__ SE) {
  __shared__ short As[2][128*64];
  __shared__ short Bs[2][128*64];
  __shared__ float xred[2][4][4][4];   // [wr][mi][fq][j]
  const int tid = threadIdx.x;
  const int l = tid & 63, w = tid >> 6;
  const int wr = w >> 1, wc = w & 1;
  const int mt = blockIdx.x, c = blockIdx.y;
  const short* Bq = QB + (size_t)c * Q_ * E_;

  // staging slots (linear LDS, inverse-swizzled global source)
  int srow[4], scol[4], sdst[4];
#pragma unroll
  for (int i = 0; i < 4; i++) {
    int s = i*256 + tid;
    int row = s >> 3, cp = s & 7;
    srow[i] = row;
    scol[i] = (cp ^ (row & 7)) * 8;   // source chunk offset (shorts)
    sdst[i] = s * 8;                  // LDS offset (shorts)
  }
  // swizzled fragment read offsets (shorts)
  int aoff[4][2], boff[4][2];
#pragma unroll
  for (int mi = 0; mi < 4; mi++)
#pragma unroll
    for (int ks = 0; ks < 2; ks++) {
      int chunk = ks*4 + (l >> 4);
      int rowa = wr*64 + mi*16 + (l & 15);
      aoff[mi][ks] = rowa*64 + (chunk ^ (rowa & 7))*8;
      int rowb = wc*64 + mi*16 + (l & 15);
      boff[mi][ks] = rowb*64 + (chunk ^ (rowb & 7))*8;
    }

  float rs[4][4] = {};

  for (int qb = 0; qb < 8; qb++) {
    f32x4 acc[4][4];
#pragma unroll
    for (int i = 0; i < 4; i++)
#pragma unroll
      for (int j = 0; j < 4; j++) acc[i][j] = (f32x4){0.f,0.f,0.f,0.f};

    u32x4 ra[4], rb[4];
    const size_t abase = (size_t)mt * 128 * 256;
    const size_t bbase = (size_t)qb * 128 * 256;

#define LOAD_A(KS) { _Pragma("unroll") for (int i=0;i<4;i++) ra[i] = *(const u32x4*)(A + abase + (size_t)srow[i]*256 + (KS)*64 + scol[i]); }
#define LOAD_B(KS) { _Pragma("unroll") for (int i=0;i<4;i++) rb[i] = *(const u32x4*)(Bq + bbase + (size_t)srow[i]*256 + (KS)*64 + scol[i]); }
#define WRITE_A(BUF) { _Pragma("unroll") for (int i=0;i<4;i++) *(u32x4*)(&As[BUF][0] + sdst[i]) = ra[i]; }
#define WRITE_B(BUF) { _Pragma("unroll") for (int i=0;i<4;i++) *(u32x4*)(&Bs[BUF][0] + sdst[i]) = rb[i]; }

    LOAD_A(0); WRITE_A(0);
    LOAD_B(0); WRITE_B(0);
    __syncthreads();

    for (int ks = 0; ks < 4; ks++) {
      int cur = ks & 1;
      if (ks < 3) { LOAD_A(ks+1); LOAD_B(ks+1); }
#pragma unroll
      for (int ksub = 0; ksub < 2; ksub++) {
        bf16x8 af[4], bfr[4];
#pragma unroll
        for (int mi = 0; mi < 4; mi++) af[mi]  = *(const bf16x8*)(&As[cur][0] + aoff[mi][ksub]);
#pragma unroll
        for (int ni = 0; ni < 4; ni++) bfr[ni] = *(const bf16x8*)(&Bs[cur][0] + boff[ni][ksub]);
#pragma unroll
        for (int mi = 0; mi < 4; mi++)
#pragma unroll
          for (int ni = 0; ni < 4; ni++)
            acc[mi][ni] = __builtin_amdgcn_mfma_f32_16x16x32_bf16(af[mi], bfr[ni], acc[mi][ni], 0, 0, 0);
      }
      if (ks < 3) { WRITE_A(cur ^ 1); WRITE_B(cur ^ 1); }
      __syncthreads();
    }
#undef LOAD_A
#undef LOAD_B
#undef WRITE_A
#undef WRITE_B

    // epilogue: exp2 + per-lane partial row sums
#pragma unroll
    for (int mi = 0; mi < 4; mi++)
#pragma unroll
      for (int j = 0; j < 4; j++) {
        float s = 0.f;
#pragma unroll
        for (int ni = 0; ni < 4; ni++) s += __builtin_amdgcn_exp2f(acc[mi][ni][j]);
        rs[mi][j] += s;
      }
  }

  // reduce across the 16 columns within the wave (lanes sharing l>>4)
#pragma unroll
  for (int mi = 0; mi < 4; mi++)
#pragma unroll
    for (int j = 0; j < 4; j++) {
      float v = rs[mi][j];
      v += __shfl_xor(v, 1, 64);
      v += __shfl_xor(v, 2, 64);
      v += __shfl_xor(v, 4, 64);
      v += __shfl_xor(v, 8, 64);
      rs[mi][j] = v;
    }
  // combine the two wc q-halves via LDS, then write
  if (wc == 1 && (l & 15) == 0) {
    int fq = l >> 4;
#pragma unroll
    for (int mi = 0; mi < 4; mi++)
#pragma unroll
      for (int j = 0; j < 4; j++) xred[wr][mi][fq][j] = rs[mi][j];
  }
  __syncthreads();
  if (wc == 0 && (l & 15) == 0) {
    int fq = l >> 4;
#pragma unroll
    for (int mi = 0; mi < 4; mi++)
#pragma unroll
      for (int j = 0; j < 4; j++) {
        int p = mt*128 + wr*64 + mi*16 + fq*4 + j;
        SE[(size_t)p * C_ + c] = rs[mi][j] + xred[wr][mi][fq][j];
      }
  }
}

// ---------------- pos / neg0 / neg1 logits in fp32 ----------------
__global__ void k_posneg(const float* __restrict__ FEATN, const float* __restrict__ PROT,
                         float* __restrict__ POS, float* __restrict__ NEG0,
                         float* __restrict__ NEG1) {
  __shared__ float lf[4][E_];
  int w = threadIdx.x >> 6, l = threadIdx.x & 63;
  int p = blockIdx.x * 4 + w;
  int b = p >> 10;
  float4 v = *(const float4*)(FEATN + (size_t)p*E_ + l*4);
  lf[w][l*4+0] = v.x; lf[w][l*4+1] = v.y; lf[w][l*4+2] = v.z; lf[w][l*4+3] = v.w;
  __syncthreads();
  const float* Ppos  = PROT + (size_t)(2 + b)*E_*C_;  // map=1, batch b
  const float* Pneg0 = PROT;                          // map=0, batch 0 (queue row 0)
  const float* Pneg1 = PROT + (size_t)E_*C_;          // map=0, batch 1 (queue row 1)
#pragma unroll
  for (int part = 0; part < 2; part++) {
    int cc = part*64 + l;
    if (cc < C_) {
      float ap = 0.f, an0 = 0.f, an1 = 0.f;
#pragma unroll 8
      for (int e = 0; e < E_; e++) {
        float f = lf[w][e];
        ap  += f * Ppos [(size_t)e*C_ + cc];
        an0 += f * Pneg0[(size_t)e*C_ + cc];
        an1 += f * Pneg1[(size_t)e*C_ + cc];
      }
      POS [(size_t)p*C_ + cc] = ap  * INV_TEMP;
      NEG0[(size_t)p*C_ + cc] = an0 * INV_TEMP;
      NEG1[(size_t)p*C_ + cc] = an1 * INV_TEMP;
    }
  }
}

// ---------------- masked CE, per-class accumulate ----------------
__global__ void k_loss(const float* __restrict__ SE, const float* __restrict__ POS,
                       const float* __restrict__ NEG0, const float* __restrict__ NEG1,
                       const float* __restrict__ cmap,
                       float* __restrict__ CSUM, float* __restrict__ CCNT) {
  int w = threadIdx.x >> 6, l = threadIdx.x & 63;
  int p = blockIdx.x * 4 + w;
  int b = p >> 10, h = p & 1023;
  // full SE: bf16-GEMM part minus the 2 zeroed rows, plus fp32 prototype exps
  float full0 = SE[(size_t)p*C_ + l] - 2.0f
              + expf(NEG0[(size_t)p*C_ + l]) + expf(NEG1[(size_t)p*C_ + l]);
  float full1 = 0.f;
  if (l < C_ - 64)
    full1 = SE[(size_t)p*C_ + 64 + l] - 2.0f
          + expf(NEG0[(size_t)p*C_ + 64 + l]) + expf(NEG1[(size_t)p*C_ + 64 + l]);
  float T = wred_sum(full0 + full1);
#pragma unroll
  for (int part = 0; part < 2; part++) {
    int cc = part*64 + l;
    float se = part ? full1 : full0;
    if (cc < C_) {
      float cmv = cmap[((size_t)(b*C_ + cc))*HW_ + h];
      if (cmv > 0.f) {
        float pc = POS[(size_t)p*C_ + cc];
        float tgt = (cc == 0) ? POS[(size_t)p*C_] : NEG0[(size_t)p*C_ + cc - 1];
        float ce = logf(expf(pc) + (T - se)) - tgt;
        atomicAdd(&CSUM[cc], ce);
        atomicAdd(&CCNT[cc], 1.0f);
      }
    }
  }
}

__global__ void k_final(const float* __restrict__ CSUM, const float* __restrict__ CCNT,
                        float* __restrict__ out) {
  int l = threadIdx.x;
  float s = 0.f;
  for (int c = l; c < C_; c += 64) {
    float cnt = CCNT[c];
    if (cnt > 0.f) s += CSUM[c] / fmaxf(cnt, 1.0f);
  }
  s = wred_sum(s);
  if (l == 0) out[0] = 0.01f * s;
}

// ---------------- workspace layout ----------------
static constexpr size_t OFF_SM    = 0;                          // 2048*80 f32
static constexpr size_t OFF_PROT  = OFF_SM    + 655360;         // 2*2*256*80 f32
static constexpr size_t OFF_FEATN = OFF_PROT  + 327680;         // 2048*256 f32
static constexpr size_t OFF_NORM  = OFF_FEATN + 2097152;        // 2048 f32
static constexpr size_t OFF_ABF   = OFF_NORM  + 8192;           // 2048*256 bf16
static constexpr size_t OFF_POS   = OFF_ABF   + 1048576;
static constexpr size_t OFF_NEG0  = OFF_POS   + 655360;
static constexpr size_t OFF_SE    = OFF_NEG0  + 655360;
static constexpr size_t OFF_CSUM  = OFF_SE    + 655360;
static constexpr size_t OFF_CCNT  = OFF_CSUM  + 512;
static constexpr size_t OFF_PART  = OFF_CCNT  + 512;            // 32*4*20480 f32 (reused as NEG1 later)
static constexpr size_t OFF_QB    = OFF_PART  + 10485760;       // 80*1024*256 bf16
static constexpr size_t WS_NEED   = OFF_QB    + 41943040;       // ~55.8 MB

extern "C" void kernel_launch(void* const* d_in, const int* in_sizes, int n_in,
                              void* d_out, int out_size, void* d_ws, size_t ws_size,
                              hipStream_t stream) {
  (void)in_sizes; (void)n_in; (void)out_size;
  if (ws_size < WS_NEED) return;

  const float* feature = (const float*)d_in[0];
  const float* cmap    = (const float*)d_in[1];
  const float* score   = (const float*)d_in[2];
  const float* queue   = (const float*)d_in[3];
  float* out = (float*)d_out;

  char* ws = (char*)d_ws;
  float* SM    = (float*)(ws + OFF_SM);
  float* PROT  = (float*)(ws + OFF_PROT);
  float* FEATN = (float*)(ws + OFF_FEATN);
  float* NORM  = (float*)(ws + OFF_NORM);
  __hip_bfloat16* ABF = (__hip_bfloat16*)(ws + OFF_ABF);
  float* POS   = (float*)(ws + OFF_POS);
  float* NEG0  = (float*)(ws + OFF_NEG0);
  float* SE    = (float*)(ws + OFF_SE);
  float* CSUM  = (float*)(ws + OFF_CSUM);
  float* CCNT  = (float*)(ws + OFF_CCNT);
  float* PART  = (float*)(ws + OFF_PART);
  float* NEG1  = PART;  // PART is dead after k_protred; reuse for NEG1
  __hip_bfloat16* QB = (__hip_bfloat16*)(ws + OFF_QB);

  k_zero<<<1, 128, 0, stream>>>(CSUM, CCNT);
  k_sm<<<512, 256, 0, stream>>>(score, SM);
  k_featn<<<512, 256, 0, stream>>>(feature, FEATN, NORM, ABF);
  k_protos<<<dim3(32, 2, 4), 256, 0, stream>>>(SM, cmap, FEATN, NORM, PART);
  k_protred<<<320, 256, 0, stream>>>(PART, PROT);
  k_norm<<<80, 256, 0, stream>>>(PROT);
  k_transpose<<<1024, 256, 0, stream>>>(queue, QB);
  k_gemm<<<dim3(16, 80), 256, 0, stream>>>((const short*)ABF, (const short*)QB, SE);
  k_posneg<<<512, 256, 0, stream>>>(FEATN, PROT, POS, NEG0, NEG1);
  k_loss<<<512, 256, 0, stream>>>(SE, POS, NEG0, NEG1, cmap, CSUM, CCNT);
  k_final<<<1, 64, 0, stream>>>(CSUM, CCNT, out);
}

// Round 4
// 209.445 us; speedup vs baseline: 1.0012x; 1.0012x over previous
//
#include <hip/hip_runtime.h>
#include <hip/hip_bf16.h>

// Proto contrastive loss, MI355X. B=2, E=256, HW=1024, C=80, Q=1024.
// SE[p][c] = sum_q exp(dot(featn_p, queue_qc)/TEMP); lse's collapse algebraically.
// Queue rows 0,1 handled in fp32; bf16 GEMM computes rows 2..1023 (|logit|<=1.43).
// k_gemm: A-panel resident in LDS (64KB, XOR-swizzled), B streamed dbuf (2x16KB),
// 512 thr / 8 waves (4Mx2N), 5 classes/block streamed, bijective XCD swizzle.

#define B_ 2
#define E_ 256
#define HW_ 1024
#define C_ 80
#define Q_ 1024

typedef __attribute__((ext_vector_type(4))) float f32x4;
typedef __attribute__((ext_vector_type(8))) short bf16x8;
typedef unsigned int u32;
typedef __attribute__((ext_vector_type(4))) u32 u32x4;

#define L2E 1.4426950408889634f
#define SCALE_A (L2E / 0.07f)
#define INV_TEMP (1.0f / 0.07f)

__device__ __forceinline__ ushort f2bf(float f) {
  union { __hip_bfloat16 b; ushort u; } cv;
  cv.b = __float2bfloat16(f);
  return cv.u;
}

__device__ __forceinline__ float wred_sum(float v) {
#pragma unroll
  for (int m = 1; m < 64; m <<= 1) v += __shfl_xor(v, m, 64);
  return v;
}
__device__ __forceinline__ float wred_max(float v) {
#pragma unroll
  for (int m = 1; m < 64; m <<= 1) v = fmaxf(v, __shfl_xor(v, m, 64));
  return v;
}

// ---------------- softmax(score/0.001) over C, per pixel (+ zero accumulators) ----------------
__global__ void k_sm(const float* __restrict__ score, float* __restrict__ SM,
                     float* __restrict__ CSUM, float* __restrict__ CCNT) {
  if (blockIdx.x == 0) {
    int t = threadIdx.x;
    if (t < C_) { CSUM[t] = 0.f; CCNT[t] = 0.f; }
  }
  int w = threadIdx.x >> 6, l = threadIdx.x & 63;
  int p = blockIdx.x * 4 + w;
  int b = p >> 10, h = p & 1023;
  float x0 = score[((size_t)(b*C_ + l))*HW_ + h] * 1000.0f;
  float x1 = (l < C_ - 64) ? score[((size_t)(b*C_ + 64 + l))*HW_ + h] * 1000.0f : -__builtin_inff();
  float m = wred_max(fmaxf(x0, x1));
  float e0 = __builtin_amdgcn_exp2f((x0 - m) * L2E);
  float e1 = (l < C_ - 64) ? __builtin_amdgcn_exp2f((x1 - m) * L2E) : 0.0f;
  float s = wred_sum(e0 + e1);
  float inv = 1.0f / s;
  SM[(size_t)p*C_ + l] = e0 * inv;
  if (l < C_ - 64) SM[(size_t)p*C_ + 64 + l] = e1 * inv;
}

// ---------------- per-pixel L2 norm; write featn fp32 + scaled bf16 A ----------------
__global__ void k_featn(const float* __restrict__ feat, float* __restrict__ FEATN,
                        float* __restrict__ NORM, __hip_bfloat16* __restrict__ ABF) {
  int w = threadIdx.x >> 6, l = threadIdx.x & 63;
  int p = blockIdx.x * 4 + w;
  int b = p >> 10, h = p & 1023;
  float f[4]; float ss = 0.f;
#pragma unroll
  for (int i = 0; i < 4; i++) {
    int e = l + 64*i;
    f[i] = feat[((size_t)(b*E_ + e))*HW_ + h];
    ss += f[i]*f[i];
  }
  ss = wred_sum(ss);
  float nrm = sqrtf(ss);
  float inv = 1.0f / fmaxf(nrm, 1e-5f);
#pragma unroll
  for (int i = 0; i < 4; i++) {
    int e = l + 64*i;
    float v = f[i]*inv;
    FEATN[(size_t)p*E_ + e] = v;
    ABF[(size_t)p*E_ + e] = __float2bfloat16(v * SCALE_A);
  }
  if (l == 0) NORM[p] = nrm;
}

// ---------------- prototypes: partial einsum feat * (sm|cm) ----------------
__global__ void k_protos(const float* __restrict__ SM, const float* __restrict__ cmap,
                         const float* __restrict__ FEATN, const float* __restrict__ NORM,
                         float* __restrict__ PART) {
  int hch = blockIdx.x, b = blockIdx.y;
  int map = blockIdx.z >> 1, ch = blockIdx.z & 1;
  int e = threadIdx.x;
  __shared__ float wl[64][40];
  for (int idx = threadIdx.x; idx < 64*40; idx += 256) {
    int ii = idx / 40, cl = idx % 40;
    int c = ch*40 + cl;
    int p = b*HW_ + hch*64 + ii;
    int h = p & 1023;
    float wv = (map == 0) ? SM[(size_t)p*C_ + c] : cmap[((size_t)(b*C_ + c))*HW_ + h];
    wl[ii][cl] = wv * NORM[p];
  }
  __syncthreads();
  float acc[40];
#pragma unroll
  for (int j = 0; j < 40; j++) acc[j] = 0.f;
  for (int ii = 0; ii < 64; ii++) {
    int p = b*HW_ + hch*64 + ii;
    float f = FEATN[(size_t)p*E_ + e];
#pragma unroll
    for (int j = 0; j < 40; j++) acc[j] += f * wl[ii][j];
  }
  float* out = PART + ((size_t)(hch*4 + map*2 + b)*E_ + e)*C_ + ch*40;
#pragma unroll
  for (int j = 0; j < 40; j++) out[j] = acc[j];
}

// reduce 32 chunks -> PROT[map][b][e][c]
__global__ void k_protred(const float* __restrict__ PART, float* __restrict__ PROT) {
  int g = blockIdx.x*256 + threadIdx.x;   // 81920
  float s = 0.f;
#pragma unroll 8
  for (int chk = 0; chk < 32; chk++) s += PART[(size_t)chk*81920 + g];
  PROT[g] = s;
}

// L2-normalize PROT over e for each (map,b,c)
__global__ void k_norm(float* PROT) {
  int w = threadIdx.x >> 6, l = threadIdx.x & 63;
  int gid = blockIdx.x*4 + w;          // 320
  int mb = gid / C_, c = gid % C_;
  float v[4]; float ss = 0.f;
#pragma unroll
  for (int i = 0; i < 4; i++) {
    v[i] = PROT[((size_t)(mb*E_ + l + 64*i))*C_ + c];
    ss += v[i]*v[i];
  }
  ss = wred_sum(ss);
  float inv = 1.0f / fmaxf(sqrtf(ss), 1e-5f);
#pragma unroll
  for (int i = 0; i < 4; i++)
    PROT[((size_t)(mb*E_ + l + 64*i))*C_ + c] = v[i]*inv;
}

// ---------------- queue -> bf16 [c][q][e], coalesced via LDS; rows 0,1 zeroed ----------------
__global__ void k_transpose(const float* __restrict__ queue,
                            __hip_bfloat16* __restrict__ QB) {
  __shared__ float ld[64*81];          // pad 81 -> write-phase LDS reads ~2-way
  int q = blockIdx.x, t = threadIdx.x;
  if (q < B_) {
    bf16x8 z = (bf16x8){0,0,0,0,0,0,0,0};
    for (int i = t; i < C_*E_/8; i += 256) {
      int c = i >> 5, chunk = i & 31;
      *(bf16x8*)(QB + ((size_t)c*Q_ + q)*E_ + chunk*8) = z;
    }
    return;
  }
  const float* src = queue + (size_t)q*E_*C_;
  for (int ec = 0; ec < 4; ec++) {     // e-chunks of 64
    for (int i = t; i < 1280; i += 256) {   // contiguous float4 loads
      float4 v = *(const float4*)(src + (size_t)ec*5120 + (size_t)i*4);
      int row = i / 20, col = (i % 20) * 4;
      ld[row*81 + col + 0] = v.x; ld[row*81 + col + 1] = v.y;
      ld[row*81 + col + 2] = v.z; ld[row*81 + col + 3] = v.w;
    }
    __syncthreads();
#pragma unroll
    for (int pass = 0; pass < 5; pass++) {
      int c = pass*16 + (t >> 4);
      int el = t & 15;                 // e sub-offset = el*4
      ushort4 pack;
      pack.x = f2bf(ld[(el*4 + 0)*81 + c]);
      pack.y = f2bf(ld[(el*4 + 1)*81 + c]);
      pack.z = f2bf(ld[(el*4 + 2)*81 + c]);
      pack.w = f2bf(ld[(el*4 + 3)*81 + c]);
      *(ushort4*)(QB + ((size_t)c*Q_ + q)*E_ + ec*64 + el*4) = pack;
    }
    __syncthreads();
  }
}

// ---------------- main GEMM: SE[p][c] = sum_{q>=2} exp2(acc) + 2 ----------------
__launch_bounds__(512, 1)
__global__ void k_gemm(const short* __restrict__ A, const short* __restrict__ QB,
                       float* __restrict__ SE) {
  __shared__ short As[128*256];        // 64 KB resident A panel (swizzled)
  __shared__ short Bs[2][128*64];      // 2 x 16 KB streamed B
  __shared__ float xred[4][2][4][4];   // [wr][mi][fq][j]
  const int tid = threadIdx.x;
  const int l = tid & 63, w = tid >> 6;    // 8 waves
  const int wr = w >> 1, wc = w & 1;       // 4 M x 2 N
  // bijective XCD swizzle: XCD x gets work-ids [32x, 32x+32)
  int bid = blockIdx.x;
  int wid = (bid & 7) * 32 + (bid >> 3);
  const int mt = wid & 15, c0 = (wid >> 4) * 5;

  // ---- stage A panel once (source pre-swizzled, LDS linear) ----
  {
    const size_t abase = (size_t)mt * 128 * 256;
#pragma unroll
    for (int i = 0; i < 8; i++) {
      int s = i*512 + tid;
      int row = s >> 5, chunk = s & 31;
      int sch = (chunk & 24) | ((chunk ^ row) & 7);
      u32x4 v = *(const u32x4*)(A + abase + (size_t)row*256 + sch*8);
      *(u32x4*)(&As[0] + s*8) = v;
    }
  }

  // B staging slots
  int brow[2], bcol[2], bdst[2];
#pragma unroll
  for (int i = 0; i < 2; i++) {
    int s = i*512 + tid;
    int row = s >> 3, cp = s & 7;
    brow[i] = row;
    bcol[i] = ((cp ^ row) & 7) * 8;
    bdst[i] = s * 8;
  }
  // fragment read offsets
  const int fq = l >> 4;
  int aoff[2][4][2];
#pragma unroll
  for (int mi = 0; mi < 2; mi++) {
    int rowa = wr*32 + mi*16 + (l & 15);
#pragma unroll
    for (int ks = 0; ks < 4; ks++)
#pragma unroll
      for (int ksub = 0; ksub < 2; ksub++) {
        int chunk = ks*8 + ksub*4 + fq;
        aoff[mi][ks][ksub] = rowa*256 + ((chunk & 24) | ((chunk ^ rowa) & 7))*8;
      }
  }
  int boff[4][2];
#pragma unroll
  for (int ni = 0; ni < 4; ni++) {
    int rowb = wc*64 + ni*16 + (l & 15);
#pragma unroll
    for (int ksub = 0; ksub < 2; ksub++) {
      int chunk = ksub*4 + fq;
      boff[ni][ksub] = rowb*64 + ((chunk ^ rowb) & 7)*8;
    }
  }

  f32x4 acc[2][4];
  float rs[2][4];
  u32x4 rb[2];
#pragma unroll
  for (int mi = 0; mi < 2; mi++)
#pragma unroll
    for (int ni = 0; ni < 4; ni++) acc[mi][ni] = (f32x4){0.f,0.f,0.f,0.f};
#pragma unroll
  for (int mi = 0; mi < 2; mi++)
#pragma unroll
    for (int j = 0; j < 4; j++) rs[mi][j] = 0.f;

  // step u in [0,160): cls = u>>5, qb = (u>>2)&7, ks = u&3
#define BSRC(U, I) (QB + ((size_t)(c0 + ((U) >> 5)) * 1024 + (((U) >> 2) & 7) * 128 + brow[I]) * 256 + ((U) & 3) * 64 + bcol[I])
#define LOADB(U)  { rb[0] = *(const u32x4*)BSRC(U,0); rb[1] = *(const u32x4*)BSRC(U,1); }
#define WRITEB(BUF) { *(u32x4*)(&Bs[BUF][0] + bdst[0]) = rb[0]; *(u32x4*)(&Bs[BUF][0] + bdst[1]) = rb[1]; }

  LOADB(0); WRITEB(0);
  __syncthreads();      // A + B step 0 ready

  for (int u = 0; u < 160; u++) {
    const int cur = u & 1;
    const int ks = u & 3;
    if (u < 159) LOADB(u+1);
#pragma unroll
    for (int ksub = 0; ksub < 2; ksub++) {
      bf16x8 af[2], bfr[4];
#pragma unroll
      for (int mi = 0; mi < 2; mi++) af[mi]  = *(const bf16x8*)(&As[0] + aoff[mi][ks][ksub]);
#pragma unroll
      for (int ni = 0; ni < 4; ni++) bfr[ni] = *(const bf16x8*)(&Bs[cur][0] + boff[ni][ksub]);
#pragma unroll
      for (int mi = 0; mi < 2; mi++)
#pragma unroll
        for (int ni = 0; ni < 4; ni++)
          acc[mi][ni] = __builtin_amdgcn_mfma_f32_16x16x32_bf16(af[mi], bfr[ni], acc[mi][ni], 0, 0, 0);
    }
    if (ks == 3) {       // q-tile done: exp2 into rs, reset acc
#pragma unroll
      for (int mi = 0; mi < 2; mi++)
#pragma unroll
        for (int j = 0; j < 4; j++) {
          float s = 0.f;
#pragma unroll
          for (int ni = 0; ni < 4; ni++) s += __builtin_amdgcn_exp2f(acc[mi][ni][j]);
          rs[mi][j] += s;
#pragma unroll
          for (int ni = 0; ni < 4; ni++) acc[mi][ni][j] = 0.f;
        }
    }
    if (u < 159) WRITEB(cur ^ 1);
    __syncthreads();

    if ((u & 31) == 31) {            // class done: reduce + write SE column
      int cls = u >> 5;
      float v[2][4];
#pragma unroll
      for (int mi = 0; mi < 2; mi++)
#pragma unroll
        for (int j = 0; j < 4; j++) {
          float x = rs[mi][j];
          x += __shfl_xor(x, 1, 64);
          x += __shfl_xor(x, 2, 64);
          x += __shfl_xor(x, 4, 64);
          x += __shfl_xor(x, 8, 64);
          v[mi][j] = x;
          rs[mi][j] = 0.f;
        }
      if (wc == 1 && (l & 15) == 0) {
#pragma unroll
        for (int mi = 0; mi < 2; mi++)
#pragma unroll
          for (int j = 0; j < 4; j++) xred[wr][mi][fq][j] = v[mi][j];
      }
      __syncthreads();
      if (wc == 0 && (l & 15) == 0) {
#pragma unroll
        for (int mi = 0; mi < 2; mi++)
#pragma unroll
          for (int j = 0; j < 4; j++) {
            int p = mt*128 + wr*32 + mi*16 + fq*4 + j;
            SE[(size_t)p * C_ + c0 + cls] = v[mi][j] + xred[wr][mi][fq][j];
          }
      }
      __syncthreads();
    }
  }
#undef BSRC
#undef LOADB
#undef WRITEB
}

// ---------------- fused pos/neg + masked CE ----------------
__global__ void k_lossf(const float* __restrict__ FEATN, const float* __restrict__ PROT,
                        const float* __restrict__ SE, const float* __restrict__ cmap,
                        float* __restrict__ CSUM, float* __restrict__ CCNT) {
  __shared__ float lf[4][E_];
  int w = threadIdx.x >> 6, l = threadIdx.x & 63;
  int p = blockIdx.x * 4 + w;
  int b = p >> 10, h = p & 1023;
  float4 v = *(const float4*)(FEATN + (size_t)p*E_ + l*4);
  lf[w][l*4+0] = v.x; lf[w][l*4+1] = v.y; lf[w][l*4+2] = v.z; lf[w][l*4+3] = v.w;
  __syncthreads();
  const float* Ppos  = PROT + (size_t)(2 + b)*E_*C_;  // map=1, batch b
  const float* Pneg0 = PROT;                          // map=0, batch 0 (queue row 0)
  const float* Pneg1 = PROT + (size_t)E_*C_;          // map=0, batch 1 (queue row 1)
  float ap[2] = {0.f, 0.f}, an0[2] = {0.f, 0.f}, an1[2] = {0.f, 0.f};
#pragma unroll
  for (int part = 0; part < 2; part++) {
    int cc = part*64 + l;
    if (cc < C_) {
      float a = 0.f, n0 = 0.f, n1 = 0.f;
#pragma unroll 8
      for (int e = 0; e < E_; e++) {
        float f = lf[w][e];
        a  += f * Ppos [(size_t)e*C_ + cc];
        n0 += f * Pneg0[(size_t)e*C_ + cc];
        n1 += f * Pneg1[(size_t)e*C_ + cc];
      }
      ap[part] = a * INV_TEMP; an0[part] = n0 * INV_TEMP; an1[part] = n1 * INV_TEMP;
    }
  }
  float pos0    = __shfl(ap[0], 0, 64);
  float n0m1_p0 = __shfl(an0[0], (l + 63) & 63, 64);
  float n0m1_p1 = __shfl(an0[1], (l + 63) & 63, 64);
  float n0_63   = __shfl(an0[0], 63, 64);
  // SE from GEMM covers q>=2 plus the 2 zeroed rows; swap in exact fp32 proto exps
  float full0 = SE[(size_t)p*C_ + l] - 2.0f + expf(an0[0]) + expf(an1[0]);
  float full1 = (l < C_ - 64)
              ? SE[(size_t)p*C_ + 64 + l] - 2.0f + expf(an0[1]) + expf(an1[1]) : 0.f;
  float T = wred_sum(full0 + full1);
#pragma unroll
  for (int part = 0; part < 2; part++) {
    int cc = part*64 + l;
    if (cc < C_) {
      float cmv = cmap[((size_t)(b*C_ + cc))*HW_ + h];
      if (cmv > 0.f) {
        float se = part ? full1 : full0;
        float pc = ap[part];
        float tgt = (part == 0) ? ((cc == 0) ? pos0 : n0m1_p0)
                                : ((l == 0) ? n0_63 : n0m1_p1);
        float ce = logf(expf(pc) + (T - se)) - tgt;
        atomicAdd(&CSUM[cc], ce);
        atomicAdd(&CCNT[cc], 1.0f);
      }
    }
  }
}

__global__ void k_final(const float* __restrict__ CSUM, const float* __restrict__ CCNT,
                        float* __restrict__ out) {
  int l = threadIdx.x;
  float s = 0.f;
  for (int c = l; c < C_; c += 64) {
    float cnt = CCNT[c];
    if (cnt > 0.f) s += CSUM[c] / fmaxf(cnt, 1.0f);
  }
  s = wred_sum(s);
  if (l == 0) out[0] = 0.01f * s;
}

// ---------------- workspace layout ----------------
static constexpr size_t OFF_SM    = 0;                          // 2048*80 f32
static constexpr size_t OFF_PROT  = OFF_SM    + 655360;         // 2*2*256*80 f32
static constexpr size_t OFF_FEATN = OFF_PROT  + 327680;         // 2048*256 f32
static constexpr size_t OFF_NORM  = OFF_FEATN + 2097152;        // 2048 f32
static constexpr size_t OFF_ABF   = OFF_NORM  + 8192;           // 2048*256 bf16
static constexpr size_t OFF_SE    = OFF_ABF   + 1048576;        // 2048*80 f32
static constexpr size_t OFF_CSUM  = OFF_SE    + 655360;
static constexpr size_t OFF_CCNT  = OFF_CSUM  + 512;
static constexpr size_t OFF_PART  = OFF_CCNT  + 512;            // 32*4*20480 f32
static constexpr size_t OFF_QB    = OFF_PART  + 10485760;       // 80*1024*256 bf16
static constexpr size_t WS_NEED   = OFF_QB    + 41943040;       // ~54 MB

extern "C" void kernel_launch(void* const* d_in, const int* in_sizes, int n_in,
                              void* d_out, int out_size, void* d_ws, size_t ws_size,
                              hipStream_t stream) {
  (void)in_sizes; (void)n_in; (void)out_size;
  if (ws_size < WS_NEED) return;

  const float* feature = (const float*)d_in[0];
  const float* cmap    = (const float*)d_in[1];
  const float* score   = (const float*)d_in[2];
  const float* queue   = (const float*)d_in[3];
  float* out = (float*)d_out;

  char* ws = (char*)d_ws;
  float* SM    = (float*)(ws + OFF_SM);
  float* PROT  = (float*)(ws + OFF_PROT);
  float* FEATN = (float*)(ws + OFF_FEATN);
  float* NORM  = (float*)(ws + OFF_NORM);
  __hip_bfloat16* ABF = (__hip_bfloat16*)(ws + OFF_ABF);
  float* SE    = (float*)(ws + OFF_SE);
  float* CSUM  = (float*)(ws + OFF_CSUM);
  float* CCNT  = (float*)(ws + OFF_CCNT);
  float* PART  = (float*)(ws + OFF_PART);
  __hip_bfloat16* QB = (__hip_bfloat16*)(ws + OFF_QB);

  k_sm<<<512, 256, 0, stream>>>(score, SM, CSUM, CCNT);
  k_featn<<<512, 256, 0, stream>>>(feature, FEATN, NORM, ABF);
  k_protos<<<dim3(32, 2, 4), 256, 0, stream>>>(SM, cmap, FEATN, NORM, PART);
  k_protred<<<320, 256, 0, stream>>>(PART, PROT);
  k_norm<<<80, 256, 0, stream>>>(PROT);
  k_transpose<<<1024, 256, 0, stream>>>(queue, QB);
  k_gemm<<<256, 512, 0, stream>>>((const short*)ABF, (const short*)QB, SE);
  k_lossf<<<512, 256, 0, stream>>>(FEATN, PROT, SE, cmap, CSUM, CCNT);
  k_final<<<1, 64, 0, stream>>>(CSUM, CCNT, out);
}